// Round 2
// baseline (12130.195 us; speedup 1.0000x reference)
//
#include <hip/hip_runtime.h>
#include <math.h>

#define H 64
#define SEQ_T 1024
#define BATCH 512
#define BPB 2
#define NTHR (BPB * H)      // 128 threads
#define NBLK (BATCH / BPB)  // 256 blocks

__device__ __forceinline__ float sigmoid_f(float v) {
    return 1.0f / (1.0f + __expf(-v));
}

// overflow-safe tanh via exp2-backed __expf: exp overflow -> inf -> 2/inf = 0 -> 1
__device__ __forceinline__ float tanh_f(float v) {
    float ax = fabsf(v);
    float e = __expf(2.0f * ax);
    float t = 1.0f - 2.0f / (e + 1.0f);
    return copysignf(t, v);
}

__global__ __launch_bounds__(NTHR) void gru_all_kernel(
    const float* __restrict__ x,
    const float* __restrict__ w_ih0, const float* __restrict__ w_hh0,
    const float* __restrict__ b_ih0, const float* __restrict__ b_hh0,
    const float* __restrict__ w_ih, const float* __restrict__ w_hh,
    const float* __restrict__ b_ih, const float* __restrict__ b_hh,
    const float* __restrict__ w_fc, const float* __restrict__ b_fc,
    float* __restrict__ out, float* __restrict__ act)
{
    // pad 193: 193 % 32 == 1 -> bank = (k + j) % 32 -> 2 lanes/bank (free)
    __shared__ float wI[H][193];
    __shared__ float wH[H][193];
    __shared__ __align__(16) float hs[BPB][H];
    __shared__ __align__(16) float xs[BPB][H];

    const int tid = threadIdx.x;
    const int bi  = tid >> 6;   // batch slot within block (0..1)
    const int j   = tid & 63;   // h index
    const int b   = blockIdx.x * BPB + bi;

    float* __restrict__ actb = act + (size_t)b * (SEQ_T * H);
    const float* __restrict__ xb = x + (size_t)b * (SEQ_T * 5);

    float hlast = 0.0f;

    for (int layer = 0; layer < 5; ++layer) {
        // ---- stage weights (transposed: w*[k][g] = w[g][k]) into LDS ----
        // Safe without a pre-barrier: all reads of wI/wH in the previous
        // layer's t-loop happened before that loop's second __syncthreads().
        if (layer == 0) {
            for (int idx = tid; idx < 192 * 5; idx += NTHR) {
                int g = idx / 5;
                int k = idx - g * 5;
                wI[k][g] = w_ih0[idx];
            }
            for (int idx = tid; idx < 192 * H; idx += NTHR)
                wH[idx & 63][idx >> 6] = w_hh0[idx];
        } else {
            const float* wi = w_ih + (size_t)(layer - 1) * (192 * H);
            const float* wh = w_hh + (size_t)(layer - 1) * (192 * H);
            for (int idx = tid; idx < 192 * H; idx += NTHR) {
                wI[idx & 63][idx >> 6] = wi[idx];
                wH[idx & 63][idx >> 6] = wh[idx];
            }
        }

        // per-thread biases in registers (r/z input+hidden biases pre-summed;
        // n-gate hidden bias must stay separate: n = tanh(xn + bNi + r*(hn + bNh)))
        float bR, bZ, bNi, bNh;
        {
            const float* bip = (layer == 0) ? b_ih0 : b_ih + (layer - 1) * 192;
            const float* bhp = (layer == 0) ? b_hh0 : b_hh + (layer - 1) * 192;
            bR  = bip[j] + bhp[j];
            bZ  = bip[j + 64] + bhp[j + 64];
            bNi = bip[j + 128];
            bNh = bhp[j + 128];
        }

        hs[bi][j] = 0.0f;  // h0 = 0 for every layer

        for (int t = 0; t < SEQ_T; ++t) {
            // stage x_t into LDS (layer 0: raw input, K=5; else previous layer's h_t)
            if (layer == 0) {
                if (j < 5) xs[bi][j] = xb[t * 5 + j];
            } else {
                xs[bi][j] = actb[t * H + j];
            }
            __syncthreads();  // xs & hs ready

            // input-side gate pre-activations
            float ar = 0.f, az = 0.f, an = 0.f;
            if (layer == 0) {
                #pragma unroll
                for (int k = 0; k < 5; ++k) {
                    float xv = xs[bi][k];
                    ar = fmaf(xv, wI[k][j],       ar);
                    az = fmaf(xv, wI[k][j + 64],  az);
                    an = fmaf(xv, wI[k][j + 128], an);
                }
            } else {
                const float4* xs4 = (const float4*)(&xs[bi][0]);
                #pragma unroll
                for (int k4 = 0; k4 < H / 4; ++k4) {
                    float4 xv = xs4[k4];
                    const int k = k4 * 4;
                    ar = fmaf(xv.x, wI[k+0][j], ar); az = fmaf(xv.x, wI[k+0][j+64], az); an = fmaf(xv.x, wI[k+0][j+128], an);
                    ar = fmaf(xv.y, wI[k+1][j], ar); az = fmaf(xv.y, wI[k+1][j+64], az); an = fmaf(xv.y, wI[k+1][j+128], an);
                    ar = fmaf(xv.z, wI[k+2][j], ar); az = fmaf(xv.z, wI[k+2][j+64], az); an = fmaf(xv.z, wI[k+2][j+128], an);
                    ar = fmaf(xv.w, wI[k+3][j], ar); az = fmaf(xv.w, wI[k+3][j+64], az); an = fmaf(xv.w, wI[k+3][j+128], an);
                }
            }

            // hidden-side gate pre-activations
            float hr = 0.f, hz = 0.f, hn = 0.f;
            {
                const float4* hs4 = (const float4*)(&hs[bi][0]);
                #pragma unroll
                for (int k4 = 0; k4 < H / 4; ++k4) {
                    float4 hv = hs4[k4];
                    const int k = k4 * 4;
                    hr = fmaf(hv.x, wH[k+0][j], hr); hz = fmaf(hv.x, wH[k+0][j+64], hz); hn = fmaf(hv.x, wH[k+0][j+128], hn);
                    hr = fmaf(hv.y, wH[k+1][j], hr); hz = fmaf(hv.y, wH[k+1][j+64], hz); hn = fmaf(hv.y, wH[k+1][j+128], hn);
                    hr = fmaf(hv.z, wH[k+2][j], hr); hz = fmaf(hv.z, wH[k+2][j+64], hz); hn = fmaf(hv.z, wH[k+2][j+128], hn);
                    hr = fmaf(hv.w, wH[k+3][j], hr); hz = fmaf(hv.w, wH[k+3][j+64], hz); hn = fmaf(hv.w, wH[k+3][j+128], hn);
                }
            }

            // gates (torch order r,z,n)
            float r = sigmoid_f(ar + hr + bR);
            float z = sigmoid_f(az + hz + bZ);
            float n = tanh_f(an + bNi + r * (hn + bNh));
            float hprev = hs[bi][j];
            float hnew = (1.0f - z) * n + z * hprev;

            __syncthreads();  // all reads of hs/xs done before overwrite
            hs[bi][j] = hnew;
            actb[t * H + j] = hnew;  // in-place: read-before-write at same (b,t)
            hlast = hnew;
        }
    }

    // ---- fused FC on last timestep: out[b] = h_{T-1} . w_fc + b_fc ----
    float v = hlast * w_fc[j];
    #pragma unroll
    for (int off = 32; off > 0; off >>= 1)
        v += __shfl_down(v, off, 64);
    if (j == 0) out[b] = v + b_fc[0];
}

extern "C" void kernel_launch(void* const* d_in, const int* in_sizes, int n_in,
                              void* d_out, int out_size, void* d_ws, size_t ws_size,
                              hipStream_t stream) {
    const float* x     = (const float*)d_in[0];
    const float* w_ih0 = (const float*)d_in[1];
    const float* w_hh0 = (const float*)d_in[2];
    const float* b_ih0 = (const float*)d_in[3];
    const float* b_hh0 = (const float*)d_in[4];
    const float* w_ih  = (const float*)d_in[5];
    const float* w_hh  = (const float*)d_in[6];
    const float* b_ih  = (const float*)d_in[7];
    const float* b_hh  = (const float*)d_in[8];
    const float* w_fc  = (const float*)d_in[9];
    const float* b_fc  = (const float*)d_in[10];
    float* out = (float*)d_out;
    float* act = (float*)d_ws;  // [BATCH][SEQ_T][H] fp32 = 128 MiB

    hipLaunchKernelGGL(gru_all_kernel, dim3(NBLK), dim3(NTHR), 0, stream,
                       x, w_ih0, w_hh0, b_ih0, b_hh0,
                       w_ih, w_hh, b_ih, b_hh, w_fc, b_fc, out, act);
}

// Round 3
// 4341.307 us; speedup vs baseline: 2.7941x; 2.7941x over previous
//
#include <hip/hip_runtime.h>
#include <math.h>

#define H 64
#define SEQ_T 1024
#define BATCH 512
#define NTHR 256            // 4 waves: thread = (j = 16*wave + jl, ks = lane>>4)
#define NBLK BATCH          // 1 block = 1 batch row; 512 blocks = 2 blocks/CU

__device__ __forceinline__ float sigmoid_f(float v) {
    return 1.0f / (1.0f + __expf(-v));
}

// overflow-safe tanh: exp overflow -> inf -> 2/inf = 0 -> t=1
__device__ __forceinline__ float tanh_f(float v) {
    float ax = fabsf(v);
    float e = __expf(2.0f * ax);
    float t = 1.0f - 2.0f / (e + 1.0f);
    return copysignf(t, v);
}

__global__ __launch_bounds__(NTHR, 2) void gru_all_kernel(
    const float* __restrict__ x,
    const float* __restrict__ w_ih0, const float* __restrict__ w_hh0,
    const float* __restrict__ b_ih0, const float* __restrict__ b_hh0,
    const float* __restrict__ w_ih, const float* __restrict__ w_hh,
    const float* __restrict__ b_ih, const float* __restrict__ b_hh,
    const float* __restrict__ w_fc, const float* __restrict__ b_fc,
    float* __restrict__ out, float* __restrict__ act)
{
    __shared__ __align__(16) float hbuf[2][H];  // double-buffered hidden state (512 B)
    __shared__ float partial[4];

    const int tid  = threadIdx.x;
    const int wv   = tid >> 6;        // wave 0..3
    const int lane = tid & 63;
    const int jl   = lane & 15;
    const int ks   = lane >> 4;       // k-slice 0..3 (k in [16ks, 16ks+16))
    const int j    = wv * 16 + jl;    // output h-index this thread helps compute
    const int k0   = ks * 16;
    const int b    = blockIdx.x;

    float* __restrict__ actb = act + (size_t)b * (SEQ_T * H);
    const float* __restrict__ xb = x + (size_t)b * (SEQ_T * 5);

    float hprev = 0.0f;

    for (int layer = 0; layer < 5; ++layer) {
        // ---- weight slices -> VGPRs (reused 1024x; load cost negligible) ----
        // wHv[g][q] = w_hh_layer[g*64+j][k0+4q .. +3], same for wIv.
        float4 wIv[3][4], wHv[3][4];
        {
            const float* whp = (layer == 0) ? w_hh0 : w_hh + (size_t)(layer - 1) * (192 * H);
            #pragma unroll
            for (int g = 0; g < 3; ++g) {
                const float4* row = (const float4*)(whp + (g * 64 + j) * H + k0);
                #pragma unroll
                for (int q = 0; q < 4; ++q) wHv[g][q] = row[q];
            }
            if (layer == 0) {
                // input dim = 5: only ks==0 lanes hold nonzero weights (k 0..4)
                #pragma unroll
                for (int g = 0; g < 3; ++g) {
                    float tmp[16];
                    #pragma unroll
                    for (int k = 0; k < 16; ++k) tmp[k] = 0.0f;
                    if (ks == 0) {
                        const float* row = w_ih0 + (g * 64 + j) * 5;
                        #pragma unroll
                        for (int k = 0; k < 5; ++k) tmp[k] = row[k];
                    }
                    #pragma unroll
                    for (int q = 0; q < 4; ++q)
                        wIv[g][q] = make_float4(tmp[4*q], tmp[4*q+1], tmp[4*q+2], tmp[4*q+3]);
                }
            } else {
                const float* wip = w_ih + (size_t)(layer - 1) * (192 * H);
                #pragma unroll
                for (int g = 0; g < 3; ++g) {
                    const float4* row = (const float4*)(wip + (g * 64 + j) * H + k0);
                    #pragma unroll
                    for (int q = 0; q < 4; ++q) wIv[g][q] = row[q];
                }
            }
        }

        // biases (r/z input+hidden pre-summed; n-gate parts stay separate)
        float bR, bZ, bNi, bNh;
        {
            const float* bip = (layer == 0) ? b_ih0 : b_ih + (layer - 1) * 192;
            const float* bhp = (layer == 0) ? b_hh0 : b_hh + (layer - 1) * 192;
            bR  = bip[j] + bhp[j];
            bZ  = bip[j + 64] + bhp[j + 64];
            bNi = bip[j + 128];
            bNh = bhp[j + 128];
        }

        hprev = 0.0f;
        if (ks == 0) hbuf[0][j] = 0.0f;

        // prefetch x_0 into xcur
        float4 xcur[4], xnext[4];
        #pragma unroll
        for (int q = 0; q < 4; ++q) xcur[q] = make_float4(0.f, 0.f, 0.f, 0.f);
        if (layer == 0) {
            if (ks == 0) {
                const float* px = xb;  // t = 0
                xcur[0] = make_float4(px[0], px[1], px[2], px[3]);
                xcur[1].x = px[4];
            }
        } else {
            const float4* pa = (const float4*)(actb + k0);  // t = 0
            #pragma unroll
            for (int q = 0; q < 4; ++q) xcur[q] = pa[q];
        }
        __syncthreads();  // hbuf[0] zeroed, everyone ready

        for (int t = 0; t < SEQ_T; ++t) {
            const int pr = t & 1;        // read buffer
            const int pw = pr ^ 1;       // write buffer
            const int tp = (t < SEQ_T - 1) ? t + 1 : t;  // clamped prefetch index

            // ---- issue prefetch for t+1 (independent of serial chain) ----
            if (layer == 0) {
                #pragma unroll
                for (int q = 0; q < 4; ++q) xnext[q] = make_float4(0.f, 0.f, 0.f, 0.f);
                if (ks == 0) {
                    const float* px = xb + tp * 5;
                    xnext[0] = make_float4(px[0], px[1], px[2], px[3]);
                    xnext[1].x = px[4];
                }
            } else {
                const float4* pa = (const float4*)(actb + tp * H + k0);
                #pragma unroll
                for (int q = 0; q < 4; ++q) xnext[q] = pa[q];
            }

            // ---- read h slice from LDS (broadcast within 16-lane groups) ----
            float4 hv[4];
            {
                const float4* hb4 = (const float4*)(&hbuf[pr][k0]);
                #pragma unroll
                for (int q = 0; q < 4; ++q) hv[q] = hb4[q];
            }

            // ---- 96 FMA: 3 gates x 16 k for both matrices ----
            float ar = 0.f, az = 0.f, an = 0.f, hr = 0.f, hz = 0.f, hn = 0.f;
            #pragma unroll
            for (int q = 0; q < 4; ++q) {
                float4 xv = xcur[q];
                ar = fmaf(xv.x, wIv[0][q].x, ar); ar = fmaf(xv.y, wIv[0][q].y, ar);
                ar = fmaf(xv.z, wIv[0][q].z, ar); ar = fmaf(xv.w, wIv[0][q].w, ar);
                az = fmaf(xv.x, wIv[1][q].x, az); az = fmaf(xv.y, wIv[1][q].y, az);
                az = fmaf(xv.z, wIv[1][q].z, az); az = fmaf(xv.w, wIv[1][q].w, az);
                an = fmaf(xv.x, wIv[2][q].x, an); an = fmaf(xv.y, wIv[2][q].y, an);
                an = fmaf(xv.z, wIv[2][q].z, an); an = fmaf(xv.w, wIv[2][q].w, an);
                float4 h4 = hv[q];
                hr = fmaf(h4.x, wHv[0][q].x, hr); hr = fmaf(h4.y, wHv[0][q].y, hr);
                hr = fmaf(h4.z, wHv[0][q].z, hr); hr = fmaf(h4.w, wHv[0][q].w, hr);
                hz = fmaf(h4.x, wHv[1][q].x, hz); hz = fmaf(h4.y, wHv[1][q].y, hz);
                hz = fmaf(h4.z, wHv[1][q].z, hz); hz = fmaf(h4.w, wHv[1][q].w, hz);
                hn = fmaf(h4.x, wHv[2][q].x, hn); hn = fmaf(h4.y, wHv[2][q].y, hn);
                hn = fmaf(h4.z, wHv[2][q].z, hn); hn = fmaf(h4.w, wHv[2][q].w, hn);
            }

            // ---- butterfly reduce the 4 k-slices (all lanes end with full sums) ----
            float sR = ar + hr, sZ = az + hz, sN = an, sH = hn;
            sR += __shfl_xor(sR, 16, 64); sR += __shfl_xor(sR, 32, 64);
            sZ += __shfl_xor(sZ, 16, 64); sZ += __shfl_xor(sZ, 32, 64);
            sN += __shfl_xor(sN, 16, 64); sN += __shfl_xor(sN, 32, 64);
            sH += __shfl_xor(sH, 16, 64); sH += __shfl_xor(sH, 32, 64);

            // ---- gates (redundant across ks lanes; keeps hnew lane-local) ----
            float r = sigmoid_f(sR + bR);
            float z = sigmoid_f(sZ + bZ);
            float n = tanh_f(sN + bNi + r * (sH + bNh));
            float hnew = fmaf(z, hprev - n, n);   // (1-z)*n + z*h
            hprev = hnew;

            if (ks == 0) {
                hbuf[pw][j] = hnew;
                if (layer < 4) actb[t * H + j] = hnew;  // feed next layer (skip on last)
            }

            #pragma unroll
            for (int q = 0; q < 4; ++q) xcur[q] = xnext[q];

            __syncthreads();  // hbuf[pw] visible before next step's read
        }
    }

    // ---- fused FC on last timestep: out[b] = h . w_fc + b_fc ----
    float v = (ks == 0) ? hprev * w_fc[j] : 0.0f;
    v += __shfl_xor(v, 1, 64);
    v += __shfl_xor(v, 2, 64);
    v += __shfl_xor(v, 4, 64);
    v += __shfl_xor(v, 8, 64);
    if (lane == 0) partial[wv] = v;   // lane 0 has jl-group sum for ks==0
    __syncthreads();
    if (tid == 0) out[b] = partial[0] + partial[1] + partial[2] + partial[3] + b_fc[0];
}

extern "C" void kernel_launch(void* const* d_in, const int* in_sizes, int n_in,
                              void* d_out, int out_size, void* d_ws, size_t ws_size,
                              hipStream_t stream) {
    const float* x     = (const float*)d_in[0];
    const float* w_ih0 = (const float*)d_in[1];
    const float* w_hh0 = (const float*)d_in[2];
    const float* b_ih0 = (const float*)d_in[3];
    const float* b_hh0 = (const float*)d_in[4];
    const float* w_ih  = (const float*)d_in[5];
    const float* w_hh  = (const float*)d_in[6];
    const float* b_ih  = (const float*)d_in[7];
    const float* b_hh  = (const float*)d_in[8];
    const float* w_fc  = (const float*)d_in[9];
    const float* b_fc  = (const float*)d_in[10];
    float* out = (float*)d_out;
    float* act = (float*)d_ws;  // [BATCH][SEQ_T][H] fp32 = 128 MiB

    hipLaunchKernelGGL(gru_all_kernel, dim3(NBLK), dim3(NTHR), 0, stream,
                       x, w_ih0, w_hh0, b_ih0, b_hh0,
                       w_ih, w_hh, b_ih, b_hh, w_fc, b_fc, out, act);
}